// Round 7
// baseline (134.613 us; speedup 1.0000x reference)
//
#include <hip/hip_runtime.h>

// Problem constants (from reference)
#define R_     4096
#define C_     16384
#define B_     32
#define NB_    (C_ / B_)     // 512
#define NC_    16
#define TOTAL  (R_ * C_)     // 67108864
#define TBITS  17
#define TSIZE  (1 << TBITS)  // 131072 hash slots (load factor 0.5)

#define GRID_  2048
#define BLK_   256
#define NV_    (GRID_ * BLK_)                  // 524288 threads
#define ITERS_ (TOTAL / 4 / NV_)               // 32 float4 per thread
#define UN_    4                               // batch depth
static_assert(NV_ * ITERS_ * 4 == TOTAL, "grid must tile exactly");
static_assert(ITERS_ % UN_ == 0, "unroll divides iters");

typedef float f32x4 __attribute__((ext_vector_type(4)));

// ---------------------------------------------------------------------------
// Main dequant kernel.
//   w = centroids[searchsorted(boundaries, x)] * s,  ties DOWN (side='left')
//   x = fl32( e * fl32(1/s) )   <- matches XLA's div->mul(1/s) rewrite
// VERIFIED BITWISE (round 5, absmax 0.0). Frozen numerics:
//  - r = fl32(1/s): plain f32 IEEE divide. (R1 proved fast-math is OFF: its
//    plain '/' matched the guaranteed correctly-rounded path bitwise, so the
//    v_div_scale/fmas/fixup sequence gives exact fl32(1/s).)
//  - boundaries (c[j+1]+c[j])*0.5f ; strict '>' chain; final w*s single mul.
// This round: drop the per-iteration asm fence (was blocking load batching),
// explicit 4-deep load->div->compute->store pipeline for MLP.
// ---------------------------------------------------------------------------
__global__ __launch_bounds__(BLK_) void dequant_kernel(
    const float* __restrict__ master,
    const float* __restrict__ centroids,
    const float* __restrict__ scale,
    float* __restrict__ out)
{
    float c[NC_];
    float bnd[NC_ - 1];
#pragma unroll
    for (int j = 0; j < NC_; ++j) c[j] = centroids[j];
#pragma unroll
    for (int j = 0; j < NC_ - 1; ++j)
        bnd[j] = (c[j + 1] + c[j]) * 0.5f;   // f32 add (1 rounding), *0.5 exact

    const f32x4* m4 = reinterpret_cast<const f32x4*>(master);
    f32x4*       o4 = reinterpret_cast<f32x4*>(out);

    const int tid = blockIdx.x * BLK_ + threadIdx.x;

    for (int k0 = 0; k0 < ITERS_; k0 += UN_) {
        f32x4 v[UN_];
        float s[UN_];
        float r[UN_];

        // Batch: issue all vector + scale loads back-to-back (MLP)
#pragma unroll
        for (int u = 0; u < UN_; ++u) {
            const int i4 = tid + (k0 + u) * NV_;
            v[u] = __builtin_nontemporal_load(m4 + i4);
            s[u] = scale[i4 >> 3];
        }
        // 4 independent correctly-rounded f32 reciprocals in flight
#pragma unroll
        for (int u = 0; u < UN_; ++u)
            r[u] = 1.0f / s[u];

#pragma unroll
        for (int u = 0; u < UN_; ++u) {
            f32x4 q;
#pragma unroll
            for (int kk = 0; kk < 4; ++kk) {
                float x = (s[u] != 0.0f) ? (v[u][kk] * r[u]) : 0.0f;  // safe_div
                // idx = #{bnd[j] < x}: ties DOWN (searchsorted side='left')
                float w = c[0];
#pragma unroll
                for (int j = 0; j < NC_ - 1; ++j)
                    w = (x > bnd[j]) ? c[j + 1] : w;
                q[kk] = w * s[u];
            }
            const int i4 = tid + (k0 + u) * NV_;
            __builtin_nontemporal_store(q, o4 + i4);
        }
    }
}

// ---------------------------------------------------------------------------
// Sparse override with numpy last-write-wins semantics for duplicate indices.
// Hash table in workspace: keys[TSIZE] (init -1), vals[TSIZE] (init -1).
// Pass 1: insert key, atomicMax source-index. Pass 2: winner writes.
// ---------------------------------------------------------------------------
__global__ void hash_insert(const int* __restrict__ sidx, int ns,
                            int* __restrict__ keys, int* __restrict__ vals)
{
    int i = blockIdx.x * blockDim.x + threadIdx.x;
    if (i >= ns) return;
    int key = sidx[i];
    unsigned h = ((unsigned)key * 2654435761u) >> (32 - TBITS);
    for (;;) {
        int prev = atomicCAS(&keys[h], -1, key);
        if (prev == -1 || prev == key) {
            atomicMax(&vals[h], i);   // last occurrence (max i) wins
            return;
        }
        h = (h + 1) & (TSIZE - 1);
    }
}

__global__ void hash_scatter(const int* __restrict__ sidx,
                             const float* __restrict__ sw, int ns,
                             const int* __restrict__ keys,
                             const int* __restrict__ vals,
                             float* __restrict__ out)
{
    int i = blockIdx.x * blockDim.x + threadIdx.x;
    if (i >= ns) return;
    int key = sidx[i];
    unsigned h = ((unsigned)key * 2654435761u) >> (32 - TBITS);
    for (;;) {
        if (keys[h] == key) {
            if (vals[h] == i) out[key] = sw[i];
            return;
        }
        h = (h + 1) & (TSIZE - 1);
    }
}

// Fallback if workspace is unexpectedly tiny: sequential = last-write-wins.
__global__ void serial_scatter(const int* __restrict__ sidx,
                               const float* __restrict__ sw, int ns,
                               float* __restrict__ out)
{
    if (blockIdx.x == 0 && threadIdx.x == 0) {
        for (int i = 0; i < ns; ++i) out[sidx[i]] = sw[i];
    }
}

extern "C" void kernel_launch(void* const* d_in, const int* in_sizes, int n_in,
                              void* d_out, int out_size, void* d_ws, size_t ws_size,
                              hipStream_t stream)
{
    const float* master    = (const float*)d_in[0];
    const float* centroids = (const float*)d_in[1];
    const float* scale     = (const float*)d_in[2];
    const float* sweight   = (const float*)d_in[3];
    const int*   sidx      = (const int*)d_in[4];
    float*       out       = (float*)d_out;
    const int    ns        = in_sizes[4];

    dequant_kernel<<<GRID_, BLK_, 0, stream>>>(master, centroids, scale, out);

    const size_t table_bytes = (size_t)TSIZE * 2 * sizeof(int);
    if (ws_size >= table_bytes) {
        hipMemsetAsync(d_ws, 0xFF, table_bytes, stream);  // keys = vals = -1
        int* keys = (int*)d_ws;
        int* vals = keys + TSIZE;
        int blocks = (ns + 255) / 256;
        hash_insert<<<blocks, 256, 0, stream>>>(sidx, ns, keys, vals);
        hash_scatter<<<blocks, 256, 0, stream>>>(sidx, sweight, ns, keys, vals, out);
    } else {
        serial_scatter<<<1, 1, 0, stream>>>(sidx, sweight, ns, out);
    }
}

// Round 8
// 132.391 us; speedup vs baseline: 1.0168x; 1.0168x over previous
//
#include <hip/hip_runtime.h>

// Problem constants (from reference)
#define R_     4096
#define C_     16384
#define B_     32
#define NB_    (C_ / B_)     // 512
#define NC_    16
#define TOTAL  (R_ * C_)     // 67108864
#define TBITS  17
#define TSIZE  (1 << TBITS)  // 131072 hash slots (load factor 0.5)
#define TWORDS (TSIZE * 2)   // 262144 ints = 1 MB (keys + vals)

#define GRID_  2048
#define BLK_   256
#define NV_    (GRID_ * BLK_)                  // 524288 threads
#define ITERS_ (TOTAL / 4 / NV_)               // 32 float4 per thread
#define UN_    4                               // batch depth
static_assert(NV_ * ITERS_ * 4 == TOTAL, "grid must tile exactly");
static_assert(ITERS_ % UN_ == 0, "unroll divides iters");
static_assert(NV_ >= TWORDS, "one store per thread covers table init");

typedef float f32x4 __attribute__((ext_vector_type(4)));

// Force a wave-uniform float into an SGPR (drops VGPR pressure: c[16]+bnd[15]
// = 31 regs otherwise live in VGPRs for the whole kernel).
__device__ __forceinline__ float rfl(float x) {
    return __int_as_float(__builtin_amdgcn_readfirstlane(__float_as_int(x)));
}

// ---------------------------------------------------------------------------
// Main dequant kernel.
//   w = centroids[searchsorted(boundaries, x)] * s,  ties DOWN (side='left')
//   x = fl32( e * fl32(1/s) )   <- matches XLA's div->mul(1/s) rewrite
// VERIFIED BITWISE (round 5, absmax 0.0). Frozen numerics:
//  - r = fl32(1/s): plain f32 IEEE divide (fast-math proven OFF in R1/R3)
//  - boundaries (c[j+1]+c[j])*0.5f ; strict '>' chain; final w*s single mul.
// This round: c/bnd pinned to SGPR (occupancy), hash-table init folded in
// (kills the memset dispatch; stream order makes it visible to hash_insert).
// ---------------------------------------------------------------------------
__global__ __launch_bounds__(BLK_) void dequant_kernel(
    const float* __restrict__ master,
    const float* __restrict__ centroids,
    const float* __restrict__ scale,
    float* __restrict__ out,
    int* __restrict__ table)
{
    // Fold the 1 MB hash-table init into this kernel (one nt store for the
    // first TWORDS threads) — removes a separate fill dispatch.
    const int tid = blockIdx.x * BLK_ + threadIdx.x;
    if (tid < TWORDS) __builtin_nontemporal_store(-1, table + tid);

    float c[NC_];
    float bnd[NC_ - 1];
#pragma unroll
    for (int j = 0; j < NC_; ++j) c[j] = rfl(centroids[j]);
#pragma unroll
    for (int j = 0; j < NC_ - 1; ++j)
        bnd[j] = rfl((c[j + 1] + c[j]) * 0.5f);  // f32 add, *0.5 exact; SGPR

    const f32x4* m4 = reinterpret_cast<const f32x4*>(master);
    f32x4*       o4 = reinterpret_cast<f32x4*>(out);

    for (int k0 = 0; k0 < ITERS_; k0 += UN_) {
        f32x4 v[UN_];
        float s[UN_];
        float r[UN_];

        // Batch: issue all vector + scale loads back-to-back (MLP)
#pragma unroll
        for (int u = 0; u < UN_; ++u) {
            const int i4 = tid + (k0 + u) * NV_;
            v[u] = __builtin_nontemporal_load(m4 + i4);
            s[u] = scale[i4 >> 3];
        }
        // independent correctly-rounded f32 reciprocals in flight
#pragma unroll
        for (int u = 0; u < UN_; ++u)
            r[u] = 1.0f / s[u];

#pragma unroll
        for (int u = 0; u < UN_; ++u) {
            f32x4 q;
#pragma unroll
            for (int kk = 0; kk < 4; ++kk) {
                float x = (s[u] != 0.0f) ? (v[u][kk] * r[u]) : 0.0f;  // safe_div
                // idx = #{bnd[j] < x}: ties DOWN (searchsorted side='left')
                float w = c[0];
#pragma unroll
                for (int j = 0; j < NC_ - 1; ++j)
                    w = (x > bnd[j]) ? c[j + 1] : w;
                q[kk] = w * s[u];
            }
            const int i4 = tid + (k0 + u) * NV_;
            __builtin_nontemporal_store(q, o4 + i4);
        }
    }
}

// ---------------------------------------------------------------------------
// Sparse override with numpy last-write-wins semantics for duplicate indices.
// Hash table (init by dequant_kernel): keys[TSIZE]=-1, vals[TSIZE]=-1.
// Pass 1: insert key, atomicMax source-index. Pass 2: winner writes.
// ---------------------------------------------------------------------------
__global__ void hash_insert(const int* __restrict__ sidx, int ns,
                            int* __restrict__ keys, int* __restrict__ vals)
{
    int i = blockIdx.x * blockDim.x + threadIdx.x;
    if (i >= ns) return;
    int key = sidx[i];
    unsigned h = ((unsigned)key * 2654435761u) >> (32 - TBITS);
    for (;;) {
        int prev = atomicCAS(&keys[h], -1, key);
        if (prev == -1 || prev == key) {
            atomicMax(&vals[h], i);   // last occurrence (max i) wins
            return;
        }
        h = (h + 1) & (TSIZE - 1);
    }
}

__global__ void hash_scatter(const int* __restrict__ sidx,
                             const float* __restrict__ sw, int ns,
                             const int* __restrict__ keys,
                             const int* __restrict__ vals,
                             float* __restrict__ out)
{
    int i = blockIdx.x * blockDim.x + threadIdx.x;
    if (i >= ns) return;
    int key = sidx[i];
    unsigned h = ((unsigned)key * 2654435761u) >> (32 - TBITS);
    for (;;) {
        if (keys[h] == key) {
            if (vals[h] == i) out[key] = sw[i];
            return;
        }
        h = (h + 1) & (TSIZE - 1);
    }
}

// Fallback if workspace is unexpectedly tiny: sequential = last-write-wins.
__global__ void serial_scatter(const int* __restrict__ sidx,
                               const float* __restrict__ sw, int ns,
                               float* __restrict__ out)
{
    if (blockIdx.x == 0 && threadIdx.x == 0) {
        for (int i = 0; i < ns; ++i) out[sidx[i]] = sw[i];
    }
}

extern "C" void kernel_launch(void* const* d_in, const int* in_sizes, int n_in,
                              void* d_out, int out_size, void* d_ws, size_t ws_size,
                              hipStream_t stream)
{
    const float* master    = (const float*)d_in[0];
    const float* centroids = (const float*)d_in[1];
    const float* scale     = (const float*)d_in[2];
    const float* sweight   = (const float*)d_in[3];
    const int*   sidx      = (const int*)d_in[4];
    float*       out       = (float*)d_out;
    const int    ns        = in_sizes[4];

    const size_t table_bytes = (size_t)TWORDS * sizeof(int);
    if (ws_size >= table_bytes) {
        int* keys = (int*)d_ws;
        int* vals = keys + TSIZE;
        // dequant also initializes the hash table (saves a fill dispatch)
        dequant_kernel<<<GRID_, BLK_, 0, stream>>>(master, centroids, scale,
                                                   out, keys);
        int blocks = (ns + 255) / 256;
        hash_insert<<<blocks, 256, 0, stream>>>(sidx, ns, keys, vals);
        hash_scatter<<<blocks, 256, 0, stream>>>(sidx, sweight, ns, keys, vals, out);
    } else {
        dequant_kernel<<<GRID_, BLK_, 0, stream>>>(master, centroids, scale,
                                                   out, (int*)d_ws);
        serial_scatter<<<1, 1, 0, stream>>>(sidx, sweight, ns, out);
    }
}

// Round 9
// 130.890 us; speedup vs baseline: 1.0284x; 1.0115x over previous
//
#include <hip/hip_runtime.h>

// Problem constants (from reference)
#define R_     4096
#define C_     16384
#define B_     32
#define NB_    (C_ / B_)     // 512
#define NC_    16
#define TOTAL  (R_ * C_)     // 67108864
#define TBITS  17
#define TSIZE  (1 << TBITS)  // 131072 hash slots (load factor 0.5)
#define TWORDS (TSIZE * 2)   // 262144 ints = 1 MB (keys + vals)

#define GRID_  2048
#define BLK_   256
#define NV_    (GRID_ * BLK_)                  // 524288 threads
#define ITERS_ (TOTAL / 4 / NV_)               // 32 float4 per thread
#define UN_    2                               // batch depth (R7: deep MLP neutral)
static_assert(NV_ * ITERS_ * 4 == TOTAL, "grid must tile exactly");
static_assert(ITERS_ % UN_ == 0, "unroll divides iters");
static_assert(NV_ >= TWORDS, "one store per thread covers table init");

typedef float f32x4 __attribute__((ext_vector_type(4)));

// Force a wave-uniform float into an SGPR (keeps c[16]+bnd[15] out of VGPRs).
__device__ __forceinline__ float rfl(float x) {
    return __int_as_float(__builtin_amdgcn_readfirstlane(__float_as_int(x)));
}

// ---------------------------------------------------------------------------
// Main dequant kernel.
//   w = centroids[searchsorted(boundaries, x)] * s,  ties DOWN (side='left')
//   x = fl32( e * fl32(1/s) )   <- matches XLA's div->mul(1/s) rewrite
// VERIFIED BITWISE (round 5, absmax 0.0). Frozen numerics:
//  - r = fl32(1/s): plain f32 IEEE divide (fast-math proven OFF in R1/R3)
//  - boundaries (c[j+1]+c[j])*0.5f ; strict '>' chain; final w*s single mul.
// R9 A/B: loads go back to PLAIN (cached) — the 6.29 TB/s copy ceiling uses
// plain loads; nt evict-first on the read stream may have been the 4.6 TB/s
// drag. Stores stay nt. __launch_bounds__(256,8) pins VGPR<=64 (8 waves/SIMD).
// ---------------------------------------------------------------------------
__global__ __launch_bounds__(BLK_, 8) void dequant_kernel(
    const float* __restrict__ master,
    const float* __restrict__ centroids,
    const float* __restrict__ scale,
    float* __restrict__ out,
    int* __restrict__ table)
{
    // Fold the 1 MB hash-table init into this kernel (one store for the
    // first TWORDS threads) — removes a separate fill dispatch.
    const int tid = blockIdx.x * BLK_ + threadIdx.x;
    if (tid < TWORDS) __builtin_nontemporal_store(-1, table + tid);

    float c[NC_];
    float bnd[NC_ - 1];
#pragma unroll
    for (int j = 0; j < NC_; ++j) c[j] = rfl(centroids[j]);
#pragma unroll
    for (int j = 0; j < NC_ - 1; ++j)
        bnd[j] = rfl((c[j + 1] + c[j]) * 0.5f);  // f32 add, *0.5 exact; SGPR

    const f32x4* m4 = reinterpret_cast<const f32x4*>(master);
    f32x4*       o4 = reinterpret_cast<f32x4*>(out);

    for (int k0 = 0; k0 < ITERS_; k0 += UN_) {
        f32x4 v[UN_];
        float s[UN_];
        float r[UN_];

#pragma unroll
        for (int u = 0; u < UN_; ++u) {
            const int i4 = tid + (k0 + u) * NV_;
            v[u] = m4[i4];                 // PLAIN cached load (A/B vs nt)
            s[u] = scale[i4 >> 3];
        }
#pragma unroll
        for (int u = 0; u < UN_; ++u)
            r[u] = 1.0f / s[u];            // correctly-rounded f32 reciprocal

#pragma unroll
        for (int u = 0; u < UN_; ++u) {
            f32x4 q;
#pragma unroll
            for (int kk = 0; kk < 4; ++kk) {
                float x = (s[u] != 0.0f) ? (v[u][kk] * r[u]) : 0.0f;  // safe_div
                // idx = #{bnd[j] < x}: ties DOWN (searchsorted side='left')
                float w = c[0];
#pragma unroll
                for (int j = 0; j < NC_ - 1; ++j)
                    w = (x > bnd[j]) ? c[j + 1] : w;
                q[kk] = w * s[u];
            }
            const int i4 = tid + (k0 + u) * NV_;
            __builtin_nontemporal_store(q, o4 + i4);   // streaming store
        }
    }
}

// ---------------------------------------------------------------------------
// Sparse override with numpy last-write-wins semantics for duplicate indices.
// Hash table (init by dequant_kernel): keys[TSIZE]=-1, vals[TSIZE]=-1.
// Pass 1: insert key, atomicMax source-index. Pass 2: winner writes.
// ---------------------------------------------------------------------------
__global__ void hash_insert(const int* __restrict__ sidx, int ns,
                            int* __restrict__ keys, int* __restrict__ vals)
{
    int i = blockIdx.x * blockDim.x + threadIdx.x;
    if (i >= ns) return;
    int key = sidx[i];
    unsigned h = ((unsigned)key * 2654435761u) >> (32 - TBITS);
    for (;;) {
        int prev = atomicCAS(&keys[h], -1, key);
        if (prev == -1 || prev == key) {
            atomicMax(&vals[h], i);   // last occurrence (max i) wins
            return;
        }
        h = (h + 1) & (TSIZE - 1);
    }
}

__global__ void hash_scatter(const int* __restrict__ sidx,
                             const float* __restrict__ sw, int ns,
                             const int* __restrict__ keys,
                             const int* __restrict__ vals,
                             float* __restrict__ out)
{
    int i = blockIdx.x * blockDim.x + threadIdx.x;
    if (i >= ns) return;
    int key = sidx[i];
    unsigned h = ((unsigned)key * 2654435761u) >> (32 - TBITS);
    for (;;) {
        if (keys[h] == key) {
            if (vals[h] == i) out[key] = sw[i];
            return;
        }
        h = (h + 1) & (TSIZE - 1);
    }
}

// Fallback if workspace is unexpectedly tiny: sequential = last-write-wins.
__global__ void serial_scatter(const int* __restrict__ sidx,
                               const float* __restrict__ sw, int ns,
                               float* __restrict__ out)
{
    if (blockIdx.x == 0 && threadIdx.x == 0) {
        for (int i = 0; i < ns; ++i) out[sidx[i]] = sw[i];
    }
}

extern "C" void kernel_launch(void* const* d_in, const int* in_sizes, int n_in,
                              void* d_out, int out_size, void* d_ws, size_t ws_size,
                              hipStream_t stream)
{
    const float* master    = (const float*)d_in[0];
    const float* centroids = (const float*)d_in[1];
    const float* scale     = (const float*)d_in[2];
    const float* sweight   = (const float*)d_in[3];
    const int*   sidx      = (const int*)d_in[4];
    float*       out       = (float*)d_out;
    const int    ns        = in_sizes[4];

    const size_t table_bytes = (size_t)TWORDS * sizeof(int);
    if (ws_size >= table_bytes) {
        int* keys = (int*)d_ws;
        int* vals = keys + TSIZE;
        // dequant also initializes the hash table (saves a fill dispatch)
        dequant_kernel<<<GRID_, BLK_, 0, stream>>>(master, centroids, scale,
                                                   out, keys);
        int blocks = (ns + 255) / 256;
        hash_insert<<<blocks, 256, 0, stream>>>(sidx, ns, keys, vals);
        hash_scatter<<<blocks, 256, 0, stream>>>(sidx, sweight, ns, keys, vals, out);
    } else {
        dequant_kernel<<<GRID_, BLK_, 0, stream>>>(master, centroids, scale,
                                                   out, (int*)d_ws);
        serial_scatter<<<1, 1, 0, stream>>>(sidx, sweight, ns, out);
    }
}